// Round 3
// baseline (130.590 us; speedup 1.0000x reference)
//
#include <hip/hip_runtime.h>
#include <math.h>

#define BB 2048
#define MM 1024
#define DD 64
#define NEG_INF_F (-1e30f)

__device__ __forceinline__ float wredsum(float v) {
#pragma unroll
  for (int o = 32; o > 0; o >>= 1) v += __shfl_down(v, o);
  return v;
}
__device__ __forceinline__ float wredmax(float v) {
#pragma unroll
  for (int o = 32; o > 0; o >>= 1) v = fmaxf(v, __shfl_down(v, o));
  return v;
}

__global__ __launch_bounds__(256) void wls_fused(
    const float* __restrict__ x,       // B*M*4
    const int*   __restrict__ pad,     // B*M (bool -> int32 per harness)
    const float* __restrict__ W_in,    // 4*64
    const float* __restrict__ b_in,    // 64
    const float* __restrict__ seed,    // 64
    const float* __restrict__ Wq,      // 64*64
    const float* __restrict__ Wk,      // 64*64
    const float* __restrict__ Wv,      // 64*64
    const float* __restrict__ Wo,      // 64*64
    const float* __restrict__ b_o,     // 64
    const float* __restrict__ w_loc,   // 68
    const float* __restrict__ b_loc,   // 1
    const float* __restrict__ prelu_a, // 1
    float* __restrict__ out)           // B*4
{
  const int tid  = threadIdx.x;
  const int b    = blockIdx.x;
  const int wave = tid >> 6;
  const int lane = tid & 63;

  __shared__ float qv[DD], kqv[DD], hb[DD], pooledv[DD], featv[DD];
  __shared__ float c4s[5];
  __shared__ float rbuf[4][16];
  __shared__ float bcast[8];  // [0]=Z, [1..4]=sum(e*x), [5]=sB

  // ---- load this block's 1024 x-rows + mask into registers (coalesced) ----
  const float4* x4 = (const float4*)(x + (size_t)b * MM * 4);
  float4 xr[4];
  int mk[4];
#pragma unroll
  for (int k2 = 0; k2 < 4; ++k2) {
    xr[k2] = x4[tid + 256 * k2];
    mk[k2] = pad[(size_t)b * MM + tid + 256 * k2];
  }

  // ---- per-block constants: q = seed@Wq ; kq = Wk@q ; c4 = W_in@kq ; c0 = b_in.kq
  if (tid < DD) {
    float acc = 0.f;
    for (int e = 0; e < DD; ++e) acc += seed[e] * Wq[e * DD + tid];
    qv[tid] = acc;
  }
  __syncthreads();
  if (tid < DD) {
    float acc = 0.f;
    for (int d = 0; d < DD; ++d) acc += Wk[tid * DD + d] * qv[d];
    kqv[tid] = acc;
  }
  __syncthreads();
  if (tid < 4) {
    float acc = 0.f;
    for (int e = 0; e < DD; ++e) acc += W_in[tid * DD + e] * kqv[e];
    c4s[tid] = acc;
  } else if (tid == 4) {
    float acc = 0.f;
    for (int e = 0; e < DD; ++e) acc += b_in[e] * kqv[e];
    c4s[4] = acc;
  }
  __syncthreads();

  const float c40 = c4s[0], c41 = c4s[1], c42 = c4s[2], c43 = c4s[3], c0 = c4s[4];

  // ---- scores (x·c4 + c0)/8, masked; block max ----
  float sc[4];
  float pmax = -INFINITY;
#pragma unroll
  for (int k2 = 0; k2 < 4; ++k2) {
    float s = (xr[k2].x * c40 + xr[k2].y * c41 + xr[k2].z * c42 + xr[k2].w * c43 + c0) * 0.125f;
    if (mk[k2]) s = NEG_INF_F;
    sc[k2] = s;
    pmax = fmaxf(pmax, s);
  }
  pmax = wredmax(pmax);
  if (lane == 0) rbuf[wave][0] = pmax;
  __syncthreads();
  const float smax = fmaxf(fmaxf(rbuf[0][0], rbuf[1][0]), fmaxf(rbuf[2][0], rbuf[3][0]));
  __syncthreads();  // rbuf reused below

  // ---- softmax partials: Z = sum exp, and sum exp*x (4-vec) ----
  float se = 0.f, sx0 = 0.f, sx1 = 0.f, sx2 = 0.f, sx3 = 0.f;
#pragma unroll
  for (int k2 = 0; k2 < 4; ++k2) {
    float e = expf(sc[k2] - smax);  // masked rows: expf(-1e30) == 0
    se += e;
    sx0 += e * xr[k2].x; sx1 += e * xr[k2].y; sx2 += e * xr[k2].z; sx3 += e * xr[k2].w;
  }
  {
    float v5[5] = {se, sx0, sx1, sx2, sx3};
#pragma unroll
    for (int j = 0; j < 5; ++j) {
      float r = wredsum(v5[j]);
      if (lane == 0) rbuf[wave][j] = r;
    }
  }
  __syncthreads();
  if (tid < 5) bcast[tid] = rbuf[0][tid] + rbuf[1][tid] + rbuf[2][tid] + rbuf[3][tid];
  __syncthreads();

  // ---- feat = ((xbar@W_in + b_in)@Wv)@Wo + b_o ; sB = feat·w_loc[4:] + b_loc ----
  if (tid < DD) {
    const float Z = bcast[0];
    const float xb0 = bcast[1] / Z, xb1 = bcast[2] / Z, xb2 = bcast[3] / Z, xb3 = bcast[4] / Z;
    hb[tid] = xb0 * W_in[tid] + xb1 * W_in[DD + tid] + xb2 * W_in[2 * DD + tid] +
              xb3 * W_in[3 * DD + tid] + b_in[tid];
  }
  __syncthreads();
  if (tid < DD) {
    float acc = 0.f;
    for (int e = 0; e < DD; ++e) acc += hb[e] * Wv[e * DD + tid];
    pooledv[tid] = acc;
  }
  __syncthreads();
  if (tid < DD) {
    float acc = 0.f;
    for (int e = 0; e < DD; ++e) acc += pooledv[e] * Wo[e * DD + tid];
    featv[tid] = acc + b_o[tid];
  }
  __syncthreads();
  if (wave == 0) {
    float p = featv[lane] * w_loc[4 + lane];
    p = wredsum(p);
    if (lane == 0) bcast[5] = p + b_loc[0];
  }
  __syncthreads();

  // ---- WLS accumulation: G = sum w^2 A A^T (10), rhs = sum w^2 A r (4) ----
  const float sB = bcast[5];
  const float aP = prelu_a[0];
  const float wl0 = w_loc[0], wl1 = w_loc[1], wl2 = w_loc[2], wl3 = w_loc[3];

  float g0 = 0.f, g1 = 0.f, g2 = 0.f, g3 = 0.f, g4 = 0.f, g5 = 0.f, g6 = 0.f,
        g7 = 0.f, g8 = 0.f, g9 = 0.f, r0 = 0.f, r1 = 0.f, r2 = 0.f, r3 = 0.f;
#pragma unroll
  for (int k2 = 0; k2 < 4; ++k2) {
    const float x0 = xr[k2].x, x1 = xr[k2].y, x2 = xr[k2].z, x3 = xr[k2].w;
    float z = x0 * wl0 + x1 * wl1 + x2 * wl2 + x3 * wl3 + sB;
    float w = (z >= 0.f) ? z : aP * z;
    if (mk[k2]) w = 0.f;
    const float w2 = w * w;
    // A = (-x1,-x2,-x3,1), r = x0
    g0 += w2 * x1 * x1; g1 += w2 * x1 * x2; g2 += w2 * x1 * x3; g3 -= w2 * x1;
    g4 += w2 * x2 * x2; g5 += w2 * x2 * x3; g6 -= w2 * x2;
    g7 += w2 * x3 * x3; g8 -= w2 * x3;
    g9 += w2;
    r0 -= w2 * x1 * x0; r1 -= w2 * x2 * x0; r2 -= w2 * x3 * x0; r3 += w2 * x0;
  }
  {
    float vals[14] = {g0, g1, g2, g3, g4, g5, g6, g7, g8, g9, r0, r1, r2, r3};
#pragma unroll
    for (int j = 0; j < 14; ++j) {
      float r = wredsum(vals[j]);
      if (lane == 0) rbuf[wave][j] = r;
    }
  }
  __syncthreads();

  // ---- solve 4x4 (double, partial pivoting) on thread 0 ----
  if (tid == 0) {
    double s14[14];
#pragma unroll
    for (int j = 0; j < 14; ++j)
      s14[j] = (double)rbuf[0][j] + (double)rbuf[1][j] +
               (double)rbuf[2][j] + (double)rbuf[3][j];
    double G[4][5];
    G[0][0] = s14[0]; G[0][1] = s14[1]; G[0][2] = s14[2]; G[0][3] = s14[3]; G[0][4] = s14[10];
    G[1][0] = s14[1]; G[1][1] = s14[4]; G[1][2] = s14[5]; G[1][3] = s14[6]; G[1][4] = s14[11];
    G[2][0] = s14[2]; G[2][1] = s14[5]; G[2][2] = s14[7]; G[2][3] = s14[8]; G[2][4] = s14[12];
    G[3][0] = s14[3]; G[3][1] = s14[6]; G[3][2] = s14[8]; G[3][3] = s14[9]; G[3][4] = s14[13];

    for (int c = 0; c < 4; ++c) {
      int p = c; double mv = fabs(G[c][c]);
      for (int rr = c + 1; rr < 4; ++rr)
        if (fabs(G[rr][c]) > mv) { mv = fabs(G[rr][c]); p = rr; }
      if (p != c)
        for (int j = c; j < 5; ++j) { double t = G[c][j]; G[c][j] = G[p][j]; G[p][j] = t; }
      const double inv = 1.0 / G[c][c];
      for (int rr = c + 1; rr < 4; ++rr) {
        const double f = G[rr][c] * inv;
        for (int j = c; j < 5; ++j) G[rr][j] -= f * G[c][j];
      }
    }
    double y[4];
    for (int c = 3; c >= 0; --c) {
      double acc = G[c][4];
      for (int j = c + 1; j < 4; ++j) acc -= G[c][j] * y[j];
      y[c] = acc / G[c][c];
    }
    float4 o;
    o.x = (float)y[0]; o.y = (float)y[1]; o.z = (float)y[2]; o.w = (float)y[3];
    *(float4*)(out + (size_t)b * 4) = o;
  }
}

extern "C" void kernel_launch(void* const* d_in, const int* in_sizes, int n_in,
                              void* d_out, int out_size, void* d_ws, size_t ws_size,
                              hipStream_t stream) {
  const float* x       = (const float*)d_in[0];
  const int*   pad     = (const int*)d_in[1];
  const float* W_in    = (const float*)d_in[2];
  const float* b_in    = (const float*)d_in[3];
  const float* seed    = (const float*)d_in[4];
  const float* Wq      = (const float*)d_in[5];
  const float* Wk      = (const float*)d_in[6];
  const float* Wv      = (const float*)d_in[7];
  const float* Wo      = (const float*)d_in[8];
  const float* b_o     = (const float*)d_in[9];
  const float* w_loc   = (const float*)d_in[10];
  const float* b_loc   = (const float*)d_in[11];
  const float* prelu_a = (const float*)d_in[12];
  float* out = (float*)d_out;

  wls_fused<<<dim3(BB), dim3(256), 0, stream>>>(
      x, pad, W_in, b_in, seed, Wq, Wk, Wv, Wo, b_o, w_loc, b_loc, prelu_a, out);
}